// Round 4
// baseline (2019.115 us; speedup 1.0000x reference)
//
#include <hip/hip_runtime.h>
#include <hip/hip_bf16.h>
#include <stdint.h>

#define NN 100000   // nodes
#define DD 128      // input dim
#define OO 128      // output dim
#define NS 8        // relations
#define NB 4        // bases
#define CAP 32      // per-row bucket slots (Poisson(16) tail @32 ~ 2e-4 -> ~200 overflow edges, handled)
#define CSTR 32     // ints per counter slot: 128B/counter, spreads atomics over 100K lines

typedef __attribute__((ext_vector_type(8))) short short8;
typedef __attribute__((ext_vector_type(4))) float f32x4;

__device__ __forceinline__ float bf2f(uint16_t u){
  union { uint32_t i; float f; } x; x.i = ((uint32_t)u) << 16; return x.f;
}
__device__ __forceinline__ uint16_t f2bf(float f){
  union { float f; uint32_t i; } x; x.f = f;
  uint32_t r = (x.i + 0x7FFFu + ((x.i >> 16) & 1u)) >> 16;  // RNE
  return (uint16_t)r;
}

// ---- cast features f32 -> bf16 ----
__global__ void cast_bf16_kernel(const float* __restrict__ in, uint16_t* __restrict__ out, int n4){
  int i = blockIdx.x * blockDim.x + threadIdx.x;
  if (i < n4){
    float4 v = ((const float4*)in)[i];
    ushort4 o;
    o.x = f2bf(v.x); o.y = f2bf(v.y); o.z = f2bf(v.z); o.w = f2bf(v.w);
    ((ushort4*)out)[i] = o;
  }
}

// ---- effective per-relation weight, TRANSPOSED: Vt[s][o][d] = M_s[d][o] ----
// M_s[d,o] = sum_b W_comp[d&7, b] * W[b*128 + s*16 + (d>>3), o]  (validated R1-R3)
__global__ void vt_kernel(const float* __restrict__ W, const float* __restrict__ Wc,
                          uint16_t* __restrict__ Vt){
  int d  = threadIdx.x;        // 0..127
  int so = blockIdx.x;         // s*128 + o
  int s = so >> 7, o = so & 127;
  int wrow = s * 16 + (d >> 3);
  int wci  = (d & 7) * NB;
  float acc = 0.f;
#pragma unroll
  for (int b = 0; b < NB; ++b)
    acc += Wc[wci + b] * W[(b * DD + wrow) * OO + o];
  Vt[so * DD + d] = f2bf(acc);
}

// ---- H_s = X @ M_s  (bf16 MFMA, fp32 accum; validated R1-R3) ----
__global__ __launch_bounds__(256) void gemm_kernel(const uint16_t* __restrict__ X16,
                                                   const uint16_t* __restrict__ VtS,
                                                   uint16_t* __restrict__ H16){
  const int wave = threadIdx.x >> 6;
  const int lane = threadIdx.x & 63;
  const int lr = lane & 15, lk = lane >> 4;
  const int row0 = blockIdx.x * 64 + wave * 16;
  f32x4 acc[8];
#pragma unroll
  for (int t = 0; t < 8; ++t) acc[t] = (f32x4){0.f, 0.f, 0.f, 0.f};
  int arow = row0 + lr; if (arow >= NN) arow = NN - 1;
  const uint16_t* aptr = X16 + (size_t)arow * DD + lk * 8;
#pragma unroll
  for (int kb = 0; kb < DD; kb += 32){
    short8 a = *(const short8*)(aptr + kb);
#pragma unroll
    for (int t = 0; t < 8; ++t){
      short8 b = *(const short8*)(VtS + (size_t)(t * 16 + lr) * DD + kb + lk * 8);
      acc[t] = __builtin_amdgcn_mfma_f32_16x16x32_bf16(a, b, acc[t], 0, 0, 0);
    }
  }
#pragma unroll
  for (int t = 0; t < 8; ++t){
#pragma unroll
    for (int j = 0; j < 4; ++j){
      int r = row0 + lk * 4 + j;
      if (r < NN) H16[(size_t)r * OO + t * 16 + lr] = f2bf(acc[t][j]);
    }
  }
}

__device__ __noinline__ void overflow_add(int r, int c, float v,
                                          const uint16_t* __restrict__ H16,
                                          float* __restrict__ out){
  const uint16_t* h = H16 + (size_t)c * OO;
  float* dst = out + (size_t)r * OO;
  for (int d = 0; d < OO; ++d) unsafeAtomicAdd(dst + d, v * bf2f(h[d]));
}

// ---- scatter, 4-edge ILP + line-padded counters ----
__global__ __launch_bounds__(256) void scatter4_kernel(const int* __restrict__ rows,
                                                       const int* __restrict__ cols,
                                                       const float* __restrict__ vals,
                                                       const uint16_t* __restrict__ H16,
                                                       int* __restrict__ cnt,
                                                       int2* __restrict__ pay,
                                                       float* __restrict__ out, int E){
  int t = blockIdx.x * blockDim.x + threadIdx.x;
  int e0 = t * 4;
  if (e0 >= E) return;
  if (e0 + 3 < E){
    int4   r4 = *(const int4*)(rows + e0);
    int4   c4 = *(const int4*)(cols + e0);
    float4 v4 = *(const float4*)(vals + e0);
    int p0 = atomicAdd(cnt + (size_t)r4.x * CSTR, 1);
    int p1 = atomicAdd(cnt + (size_t)r4.y * CSTR, 1);
    int p2 = atomicAdd(cnt + (size_t)r4.z * CSTR, 1);
    int p3 = atomicAdd(cnt + (size_t)r4.w * CSTR, 1);
    if (p0 < CAP) pay[(size_t)r4.x * CAP + p0] = make_int2(c4.x, __float_as_int(v4.x));
    else overflow_add(r4.x, c4.x, v4.x, H16, out);
    if (p1 < CAP) pay[(size_t)r4.y * CAP + p1] = make_int2(c4.y, __float_as_int(v4.y));
    else overflow_add(r4.y, c4.y, v4.y, H16, out);
    if (p2 < CAP) pay[(size_t)r4.z * CAP + p2] = make_int2(c4.z, __float_as_int(v4.z));
    else overflow_add(r4.z, c4.z, v4.z, H16, out);
    if (p3 < CAP) pay[(size_t)r4.w * CAP + p3] = make_int2(c4.w, __float_as_int(v4.w));
    else overflow_add(r4.w, c4.w, v4.w, H16, out);
  } else {
    for (int e = e0; e < E; ++e){
      int r = rows[e], c = cols[e];
      float v = vals[e];
      int pos = atomicAdd(cnt + (size_t)r * CSTR, 1);
      if (pos < CAP) pay[(size_t)r * CAP + pos] = make_int2(c, __float_as_int(v));
      else overflow_add(r, c, v, H16, out);
    }
  }
}

// ---- gather: one wave per row, k-unroll x4, zeroes cnt for next pass, relu on last ----
template<bool LAST>
__global__ __launch_bounds__(256) void gatherz_kernel(int* __restrict__ cnt,
                                                      const int2* __restrict__ pay,
                                                      const uint16_t* __restrict__ H16,
                                                      float* __restrict__ out){
  const int lane = threadIdx.x & 63;
  const int row  = blockIdx.x * 4 + (threadIdx.x >> 6);
  if (row >= NN) return;
  int deg = cnt[(size_t)row * CSTR];
  if (lane == 0) cnt[(size_t)row * CSTR] = 0;          // free re-zero for next pass
  if (deg > CAP) deg = CAP;

  float2 acc = *(const float2*)(out + (size_t)row * OO + lane * 2);
  int2 p = make_int2(0, 0);
  if (lane < deg) p = pay[(size_t)row * CAP + lane];
  const uint16_t* hb = H16 + lane * 2;

  int k = 0;
  for (; k + 4 <= deg; k += 4){
    int   c0 = __builtin_amdgcn_readlane(p.x, k);
    int   c1 = __builtin_amdgcn_readlane(p.x, k + 1);
    int   c2 = __builtin_amdgcn_readlane(p.x, k + 2);
    int   c3 = __builtin_amdgcn_readlane(p.x, k + 3);
    float v0 = __int_as_float(__builtin_amdgcn_readlane(p.y, k));
    float v1 = __int_as_float(__builtin_amdgcn_readlane(p.y, k + 1));
    float v2 = __int_as_float(__builtin_amdgcn_readlane(p.y, k + 2));
    float v3 = __int_as_float(__builtin_amdgcn_readlane(p.y, k + 3));
    uint32_t q0 = *(const uint32_t*)(hb + (size_t)c0 * OO);
    uint32_t q1 = *(const uint32_t*)(hb + (size_t)c1 * OO);
    uint32_t q2 = *(const uint32_t*)(hb + (size_t)c2 * OO);
    uint32_t q3 = *(const uint32_t*)(hb + (size_t)c3 * OO);
    acc.x += v0 * bf2f((uint16_t)(q0 & 0xFFFFu));  acc.y += v0 * bf2f((uint16_t)(q0 >> 16));
    acc.x += v1 * bf2f((uint16_t)(q1 & 0xFFFFu));  acc.y += v1 * bf2f((uint16_t)(q1 >> 16));
    acc.x += v2 * bf2f((uint16_t)(q2 & 0xFFFFu));  acc.y += v2 * bf2f((uint16_t)(q2 >> 16));
    acc.x += v3 * bf2f((uint16_t)(q3 & 0xFFFFu));  acc.y += v3 * bf2f((uint16_t)(q3 >> 16));
  }
  for (; k < deg; ++k){
    int   cc = __builtin_amdgcn_readlane(p.x, k);
    float vv = __int_as_float(__builtin_amdgcn_readlane(p.y, k));
    uint32_t q = *(const uint32_t*)(hb + (size_t)cc * OO);
    acc.x += vv * bf2f((uint16_t)(q & 0xFFFFu));
    acc.y += vv * bf2f((uint16_t)(q >> 16));
  }
  if (LAST){ acc.x = fmaxf(acc.x, 0.f); acc.y = fmaxf(acc.y, 0.f); }
  *(float2*)(out + (size_t)row * OO + lane * 2) = acc;
}

// ---- fallback atomic spmm (R0-validated, only if ws too small) ----
__global__ __launch_bounds__(256) void spmm_kernel(const int* __restrict__ rows,
                                                   const int* __restrict__ cols,
                                                   const float* __restrict__ vals,
                                                   const uint16_t* __restrict__ H16,
                                                   float* __restrict__ out, int E){
  const int lane = threadIdx.x & 63;
  const int gwave = (int)((blockIdx.x * blockDim.x + threadIdx.x) >> 6);
  const int nw = (gridDim.x * blockDim.x) >> 6;
  for (int base = gwave * 64; base < E; base += nw * 64){
    int cnt = E - base; if (cnt > 64) cnt = 64;
    int r = 0, c = 0; float v = 0.f;
    if (lane < cnt){
      r = rows[base + lane]; c = cols[base + lane]; v = vals[base + lane];
    }
    for (int k = 0; k < cnt; ++k){
      int rr = __shfl(r, k);
      int cc = __shfl(c, k);
      float vv = __shfl(v, k);
      uint32_t pair = *(const uint32_t*)(H16 + (size_t)cc * OO + lane * 2);
      float* dst = out + (size_t)rr * OO + lane * 2;
      unsafeAtomicAdd(dst,     vv * bf2f((uint16_t)(pair & 0xFFFFu)));
      unsafeAtomicAdd(dst + 1, vv * bf2f((uint16_t)(pair >> 16)));
    }
  }
}

__global__ void relu_kernel(float* __restrict__ out, int n4){
  int i = blockIdx.x * blockDim.x + threadIdx.x;
  if (i < n4){
    float4 v = ((float4*)out)[i];
    v.x = fmaxf(v.x, 0.f); v.y = fmaxf(v.y, 0.f);
    v.z = fmaxf(v.z, 0.f); v.w = fmaxf(v.w, 0.f);
    ((float4*)out)[i] = v;
  }
}

extern "C" void kernel_launch(void* const* d_in, const int* in_sizes, int n_in,
                              void* d_out, int out_size, void* d_ws, size_t ws_size,
                              hipStream_t stream){
  const float* features = (const float*)d_in[0];
  const int*   rows     = (const int*)d_in[1];
  const int*   cols     = (const int*)d_in[2];
  const float* vals     = (const float*)d_in[3];
  const float* W        = (const float*)d_in[4];
  const float* Wc       = (const float*)d_in[5];
  float* out = (float*)d_out;
  const int E = in_sizes[1] / NS;

  char* ws = (char*)d_ws;
  uint16_t* X16 = (uint16_t*)ws;                        // 25,600,000
  uint16_t* Vt  = (uint16_t*)(ws + 25600000);           //    262,144
  uint16_t* H16 = (uint16_t*)(ws + 25862144);           // 25,600,000
  int*      cnt = (int*)     (ws + 51462144);           // 12,800,000 (100K x 128B)
  int2*     pay = (int2*)    (ws + 64262144);           // 25,600,000 (100K x 32 x 8B)
  const size_t NEEDED = 64262144 + (size_t)NN * CAP * 8;   // 89,862,144 < known ws >= 90,262,144

  hipMemsetAsync(d_out, 0, (size_t)out_size * sizeof(float), stream);
  cast_bf16_kernel<<<(NN * DD / 4 + 255) / 256, 256, 0, stream>>>(features, X16, NN * DD / 4);
  vt_kernel<<<NS * OO, DD, 0, stream>>>(W, Wc, Vt);

  if (ws_size >= NEEDED){
    hipMemsetAsync(cnt, 0, (size_t)NN * CSTR * sizeof(int), stream);  // once; gather re-zeroes
    for (int s = 0; s < NS; ++s){
      gemm_kernel<<<(NN + 63) / 64, 256, 0, stream>>>(X16, Vt + (size_t)s * DD * OO, H16);
      scatter4_kernel<<<(E / 4 + 255) / 256, 256, 0, stream>>>(
          rows + (size_t)s * E, cols + (size_t)s * E, vals + (size_t)s * E,
          H16, cnt, pay, out, E);
      if (s == NS - 1)
        gatherz_kernel<true><<<(NN + 3) / 4, 256, 0, stream>>>(cnt, pay, H16, out);
      else
        gatherz_kernel<false><<<(NN + 3) / 4, 256, 0, stream>>>(cnt, pay, H16, out);
    }
  } else {
    for (int s = 0; s < NS; ++s){
      gemm_kernel<<<(NN + 63) / 64, 256, 0, stream>>>(X16, Vt + (size_t)s * DD * OO, H16);
      spmm_kernel<<<4096, 256, 0, stream>>>(rows + (size_t)s * E, cols + (size_t)s * E,
                                            vals + (size_t)s * E, H16, out, E);
    }
    relu_kernel<<<(NN * OO / 4 + 255) / 256, 256, 0, stream>>>(out, NN * OO / 4);
  }
}

// Round 5
// 1585.056 us; speedup vs baseline: 1.2738x; 1.2738x over previous
//
#include <hip/hip_runtime.h>
#include <hip/hip_bf16.h>
#include <stdint.h>

#define NN 100000   // nodes
#define DD 128      // input dim
#define OO 128      // output dim
#define NS 8        // relations
#define NB 4        // bases
#define CAP 32      // per-row bucket slots per pass (Poisson(16) tail @32 ~ 2e-5; overflow handled)

typedef __attribute__((ext_vector_type(8))) short short8;
typedef __attribute__((ext_vector_type(4))) float f32x4;

__device__ __forceinline__ float bf2f(uint16_t u){
  union { uint32_t i; float f; } x; x.i = ((uint32_t)u) << 16; return x.f;
}
__device__ __forceinline__ uint16_t f2bf(float f){
  union { float f; uint32_t i; } x; x.f = f;
  uint32_t r = (x.i + 0x7FFFu + ((x.i >> 16) & 1u)) >> 16;  // RNE
  return (uint16_t)r;
}

// ---- cast features f32 -> bf16 ----
__global__ void cast_bf16_kernel(const float* __restrict__ in, uint16_t* __restrict__ out, int n4){
  int i = blockIdx.x * blockDim.x + threadIdx.x;
  if (i < n4){
    float4 v = ((const float4*)in)[i];
    ushort4 o;
    o.x = f2bf(v.x); o.y = f2bf(v.y); o.z = f2bf(v.z); o.w = f2bf(v.w);
    ((ushort4*)out)[i] = o;
  }
}

// ---- effective per-relation weight, TRANSPOSED: Vt[s][o][d] = M_s[d][o] ----
// M_s[d,o] = sum_b W_comp[d&7, b] * W[b*128 + s*16 + (d>>3), o]  (validated R1-R4)
__global__ void vt_kernel(const float* __restrict__ W, const float* __restrict__ Wc,
                          uint16_t* __restrict__ Vt){
  int d  = threadIdx.x;
  int so = blockIdx.x;
  int s = so >> 7, o = so & 127;
  int wrow = s * 16 + (d >> 3);
  int wci  = (d & 7) * NB;
  float acc = 0.f;
#pragma unroll
  for (int b = 0; b < NB; ++b)
    acc += Wc[wci + b] * W[(b * DD + wrow) * OO + o];
  Vt[so * DD + d] = f2bf(acc);
}

// ---- H_s = X @ M_s  (bf16 MFMA, fp32 accum; validated R1-R4) ----
__global__ __launch_bounds__(256) void gemm_kernel(const uint16_t* __restrict__ X16,
                                                   const uint16_t* __restrict__ VtS,
                                                   uint16_t* __restrict__ H16){
  const int wave = threadIdx.x >> 6;
  const int lane = threadIdx.x & 63;
  const int lr = lane & 15, lk = lane >> 4;
  const int row0 = blockIdx.x * 64 + wave * 16;
  f32x4 acc[8];
#pragma unroll
  for (int t = 0; t < 8; ++t) acc[t] = (f32x4){0.f, 0.f, 0.f, 0.f};
  int arow = row0 + lr; if (arow >= NN) arow = NN - 1;
  const uint16_t* aptr = X16 + (size_t)arow * DD + lk * 8;
#pragma unroll
  for (int kb = 0; kb < DD; kb += 32){
    short8 a = *(const short8*)(aptr + kb);
#pragma unroll
    for (int t = 0; t < 8; ++t){
      short8 b = *(const short8*)(VtS + (size_t)(t * 16 + lr) * DD + kb + lk * 8);
      acc[t] = __builtin_amdgcn_mfma_f32_16x16x32_bf16(a, b, acc[t], 0, 0, 0);
    }
  }
#pragma unroll
  for (int t = 0; t < 8; ++t){
#pragma unroll
    for (int j = 0; j < 4; ++j){
      int r = row0 + lk * 4 + j;
      if (r < NN) H16[(size_t)r * OO + t * 16 + lr] = f2bf(acc[t][j]);
    }
  }
}

__device__ __noinline__ void overflow_add(int r, int c, float v,
                                          const uint16_t* __restrict__ H16,
                                          float* __restrict__ out){
  const uint16_t* h = H16 + (size_t)c * OO;
  float* dst = out + (size_t)r * OO;
  for (int d = 0; d < OO; ++d) unsafeAtomicAdd(dst + d, v * bf2f(h[d]));
}

// ---- scatter A: R2-exact (stride-1 counters, 1 edge/thread) ----
__global__ __launch_bounds__(256) void scatter_a_kernel(const int* __restrict__ rows,
                                                        const int* __restrict__ cols,
                                                        const float* __restrict__ vals,
                                                        const uint16_t* __restrict__ H16,
                                                        int* __restrict__ cnt,
                                                        int2* __restrict__ pay,
                                                        float* __restrict__ out, int E){
  int e = blockIdx.x * blockDim.x + threadIdx.x;
  if (e >= E) return;
  int r = rows[e], c = cols[e];
  float v = vals[e];
  int pos = atomicAdd(&cnt[r], 1);
  if (pos < CAP) pay[(size_t)r * CAP + pos] = make_int2(c, __float_as_int(v));
  else overflow_add(r, c, v, H16, out);
}

// ---- scatter B: identical but counters padded to one 64B line each (CSTR=16) ----
__global__ __launch_bounds__(256) void scatter_b_kernel(const int* __restrict__ rows,
                                                        const int* __restrict__ cols,
                                                        const float* __restrict__ vals,
                                                        const uint16_t* __restrict__ H16,
                                                        int* __restrict__ cnt,
                                                        int2* __restrict__ pay,
                                                        float* __restrict__ out, int E){
  int e = blockIdx.x * blockDim.x + threadIdx.x;
  if (e >= E) return;
  int r = rows[e], c = cols[e];
  float v = vals[e];
  int pos = atomicAdd(&cnt[(size_t)r * 16], 1);
  if (pos < CAP) pay[(size_t)r * CAP + pos] = make_int2(c, __float_as_int(v));
  else overflow_add(r, c, v, H16, out);
}

// ---- gather: one wave per row, k-unroll x4, zeroes this pass's counter, relu on last ----
template<bool LAST>
__global__ __launch_bounds__(256) void gatherz_kernel(int* __restrict__ cnt, int cstr,
                                                      const int2* __restrict__ pay,
                                                      const uint16_t* __restrict__ H16,
                                                      float* __restrict__ out){
  const int lane = threadIdx.x & 63;
  const int row  = blockIdx.x * 4 + (threadIdx.x >> 6);
  if (row >= NN) return;
  int deg = cnt[(size_t)row * cstr];
  if (lane == 0) cnt[(size_t)row * cstr] = 0;
  if (deg > CAP) deg = CAP;

  float2 acc = *(const float2*)(out + (size_t)row * OO + lane * 2);
  int2 p = make_int2(0, 0);
  if (lane < deg) p = pay[(size_t)row * CAP + lane];
  const uint16_t* hb = H16 + lane * 2;

  int k = 0;
  for (; k + 4 <= deg; k += 4){
    int   c0 = __builtin_amdgcn_readlane(p.x, k);
    int   c1 = __builtin_amdgcn_readlane(p.x, k + 1);
    int   c2 = __builtin_amdgcn_readlane(p.x, k + 2);
    int   c3 = __builtin_amdgcn_readlane(p.x, k + 3);
    float v0 = __int_as_float(__builtin_amdgcn_readlane(p.y, k));
    float v1 = __int_as_float(__builtin_amdgcn_readlane(p.y, k + 1));
    float v2 = __int_as_float(__builtin_amdgcn_readlane(p.y, k + 2));
    float v3 = __int_as_float(__builtin_amdgcn_readlane(p.y, k + 3));
    uint32_t q0 = *(const uint32_t*)(hb + (size_t)c0 * OO);
    uint32_t q1 = *(const uint32_t*)(hb + (size_t)c1 * OO);
    uint32_t q2 = *(const uint32_t*)(hb + (size_t)c2 * OO);
    uint32_t q3 = *(const uint32_t*)(hb + (size_t)c3 * OO);
    acc.x += v0 * bf2f((uint16_t)(q0 & 0xFFFFu));  acc.y += v0 * bf2f((uint16_t)(q0 >> 16));
    acc.x += v1 * bf2f((uint16_t)(q1 & 0xFFFFu));  acc.y += v1 * bf2f((uint16_t)(q1 >> 16));
    acc.x += v2 * bf2f((uint16_t)(q2 & 0xFFFFu));  acc.y += v2 * bf2f((uint16_t)(q2 >> 16));
    acc.x += v3 * bf2f((uint16_t)(q3 & 0xFFFFu));  acc.y += v3 * bf2f((uint16_t)(q3 >> 16));
  }
  for (; k < deg; ++k){
    int   cc = __builtin_amdgcn_readlane(p.x, k);
    float vv = __int_as_float(__builtin_amdgcn_readlane(p.y, k));
    uint32_t q = *(const uint32_t*)(hb + (size_t)cc * OO);
    acc.x += vv * bf2f((uint16_t)(q & 0xFFFFu));
    acc.y += vv * bf2f((uint16_t)(q >> 16));
  }
  if (LAST){ acc.x = fmaxf(acc.x, 0.f); acc.y = fmaxf(acc.y, 0.f); }
  *(float2*)(out + (size_t)row * OO + lane * 2) = acc;
}

// ---- fallback atomic spmm (R0-validated, only if ws too small) ----
__global__ __launch_bounds__(256) void spmm_kernel(const int* __restrict__ rows,
                                                   const int* __restrict__ cols,
                                                   const float* __restrict__ vals,
                                                   const uint16_t* __restrict__ H16,
                                                   float* __restrict__ out, int E){
  const int lane = threadIdx.x & 63;
  const int gwave = (int)((blockIdx.x * blockDim.x + threadIdx.x) >> 6);
  const int nw = (gridDim.x * blockDim.x) >> 6;
  for (int base = gwave * 64; base < E; base += nw * 64){
    int cnt = E - base; if (cnt > 64) cnt = 64;
    int r = 0, c = 0; float v = 0.f;
    if (lane < cnt){
      r = rows[base + lane]; c = cols[base + lane]; v = vals[base + lane];
    }
    for (int k = 0; k < cnt; ++k){
      int rr = __shfl(r, k);
      int cc = __shfl(c, k);
      float vv = __shfl(v, k);
      uint32_t pair = *(const uint32_t*)(H16 + (size_t)cc * OO + lane * 2);
      float* dst = out + (size_t)rr * OO + lane * 2;
      unsafeAtomicAdd(dst,     vv * bf2f((uint16_t)(pair & 0xFFFFu)));
      unsafeAtomicAdd(dst + 1, vv * bf2f((uint16_t)(pair >> 16)));
    }
  }
}

__global__ void relu_kernel(float* __restrict__ out, int n4){
  int i = blockIdx.x * blockDim.x + threadIdx.x;
  if (i < n4){
    float4 v = ((float4*)out)[i];
    v.x = fmaxf(v.x, 0.f); v.y = fmaxf(v.y, 0.f);
    v.z = fmaxf(v.z, 0.f); v.w = fmaxf(v.w, 0.f);
    ((float4*)out)[i] = v;
  }
}

extern "C" void kernel_launch(void* const* d_in, const int* in_sizes, int n_in,
                              void* d_out, int out_size, void* d_ws, size_t ws_size,
                              hipStream_t stream){
  const float* features = (const float*)d_in[0];
  const int*   rows     = (const int*)d_in[1];
  const int*   cols     = (const int*)d_in[2];
  const float* vals     = (const float*)d_in[3];
  const float* W        = (const float*)d_in[4];
  const float* Wc       = (const float*)d_in[5];
  float* out = (float*)d_out;
  const int E = in_sizes[1] / NS;

  char* ws = (char*)d_ws;
  uint16_t* X16 = (uint16_t*)ws;                        // 25,600,000
  uint16_t* Vt  = (uint16_t*)(ws + 25600000);           //    262,144
  uint16_t* H16 = (uint16_t*)(ws + 25862144);           // 25,600,000
  int*      cnt = (int*)     (ws + 51462144);           //  6,400,000 (100K x 64B)
  int2*     pay = (int2*)    (ws + 57862144);           // 25,600,000 (100K x 32 x 8B)
  const size_t NEEDED = 57862144 + (size_t)NN * CAP * 8;   // 83,462,144 <= known ws >= 90,262,144

  hipMemsetAsync(d_out, 0, (size_t)out_size * sizeof(float), stream);
  cast_bf16_kernel<<<(NN * DD / 4 + 255) / 256, 256, 0, stream>>>(features, X16, NN * DD / 4);
  vt_kernel<<<NS * OO, DD, 0, stream>>>(W, Wc, Vt);

  if (ws_size >= NEEDED){
    hipMemsetAsync(cnt, 0, (size_t)NN * 16 * sizeof(int), stream);  // once; gather re-zeroes
    for (int s = 0; s < NS; ++s){
      const int cstr = (s & 1) ? 16 : 1;   // A/B: even passes stride-1, odd passes 64B-padded
      gemm_kernel<<<(NN + 63) / 64, 256, 0, stream>>>(X16, Vt + (size_t)s * DD * OO, H16);
      if (s & 1)
        scatter_b_kernel<<<(E + 255) / 256, 256, 0, stream>>>(
            rows + (size_t)s * E, cols + (size_t)s * E, vals + (size_t)s * E,
            H16, cnt, pay, out, E);
      else
        scatter_a_kernel<<<(E + 255) / 256, 256, 0, stream>>>(
            rows + (size_t)s * E, cols + (size_t)s * E, vals + (size_t)s * E,
            H16, cnt, pay, out, E);
      if (s == NS - 1)
        gatherz_kernel<true><<<(NN + 3) / 4, 256, 0, stream>>>(cnt, cstr, pay, H16, out);
      else
        gatherz_kernel<false><<<(NN + 3) / 4, 256, 0, stream>>>(cnt, cstr, pay, H16, out);
    }
  } else {
    for (int s = 0; s < NS; ++s){
      gemm_kernel<<<(NN + 63) / 64, 256, 0, stream>>>(X16, Vt + (size_t)s * DD * OO, H16);
      spmm_kernel<<<4096, 256, 0, stream>>>(rows + (size_t)s * E, cols + (size_t)s * E,
                                            vals + (size_t)s * E, H16, out, E);
    }
    relu_kernel<<<(NN * OO / 4 + 255) / 256, 256, 0, stream>>>(out, NN * OO / 4);
  }
}

// Round 6
// 1580.008 us; speedup vs baseline: 1.2779x; 1.0032x over previous
//
#include <hip/hip_runtime.h>
#include <hip/hip_bf16.h>
#include <stdint.h>

#define NN 100000   // nodes
#define DD 128      // input dim
#define OO 128      // output dim
#define NS 8        // relations
#define NB 4        // bases
#define CAP 32      // per-row bucket slots per pass (Poisson(16) tail @32 ~1e-5; overflow handled)
#define CSTR 16     // ints per counter slot: 64B/counter (R5 A/B winner: kills atomic line contention)

typedef __attribute__((ext_vector_type(8))) short short8;
typedef __attribute__((ext_vector_type(4))) float f32x4;

__device__ __forceinline__ float bf2f(uint16_t u){
  union { uint32_t i; float f; } x; x.i = ((uint32_t)u) << 16; return x.f;
}
__device__ __forceinline__ uint16_t f2bf(float f){
  union { float f; uint32_t i; } x; x.f = f;
  uint32_t r = (x.i + 0x7FFFu + ((x.i >> 16) & 1u)) >> 16;  // RNE
  return (uint16_t)r;
}

// ---- cast features f32 -> bf16 ----
__global__ void cast_bf16_kernel(const float* __restrict__ in, uint16_t* __restrict__ out, int n4){
  int i = blockIdx.x * blockDim.x + threadIdx.x;
  if (i < n4){
    float4 v = ((const float4*)in)[i];
    ushort4 o;
    o.x = f2bf(v.x); o.y = f2bf(v.y); o.z = f2bf(v.z); o.w = f2bf(v.w);
    ((ushort4*)out)[i] = o;
  }
}

// ---- effective per-relation weight, TRANSPOSED: Vt[s][o][d] = M_s[d][o] ----
// M_s[d,o] = sum_b W_comp[d&7, b] * W[b*128 + s*16 + (d>>3), o]  (validated R1-R5)
__global__ void vt_kernel(const float* __restrict__ W, const float* __restrict__ Wc,
                          uint16_t* __restrict__ Vt){
  int d  = threadIdx.x;
  int so = blockIdx.x;
  int s = so >> 7, o = so & 127;
  int wrow = s * 16 + (d >> 3);
  int wci  = (d & 7) * NB;
  float acc = 0.f;
#pragma unroll
  for (int b = 0; b < NB; ++b)
    acc += Wc[wci + b] * W[(b * DD + wrow) * OO + o];
  Vt[so * DD + d] = f2bf(acc);
}

// ---- H_s = X @ M_s  (bf16 MFMA, fp32 accum; validated R1-R5) ----
__global__ __launch_bounds__(256) void gemm_kernel(const uint16_t* __restrict__ X16,
                                                   const uint16_t* __restrict__ VtS,
                                                   uint16_t* __restrict__ H16){
  const int wave = threadIdx.x >> 6;
  const int lane = threadIdx.x & 63;
  const int lr = lane & 15, lk = lane >> 4;
  const int row0 = blockIdx.x * 64 + wave * 16;
  f32x4 acc[8];
#pragma unroll
  for (int t = 0; t < 8; ++t) acc[t] = (f32x4){0.f, 0.f, 0.f, 0.f};
  int arow = row0 + lr; if (arow >= NN) arow = NN - 1;
  const uint16_t* aptr = X16 + (size_t)arow * DD + lk * 8;
#pragma unroll
  for (int kb = 0; kb < DD; kb += 32){
    short8 a = *(const short8*)(aptr + kb);
#pragma unroll
    for (int t = 0; t < 8; ++t){
      short8 b = *(const short8*)(VtS + (size_t)(t * 16 + lr) * DD + kb + lk * 8);
      acc[t] = __builtin_amdgcn_mfma_f32_16x16x32_bf16(a, b, acc[t], 0, 0, 0);
    }
  }
#pragma unroll
  for (int t = 0; t < 8; ++t){
#pragma unroll
    for (int j = 0; j < 4; ++j){
      int r = row0 + lk * 4 + j;
      if (r < NN) H16[(size_t)r * OO + t * 16 + lr] = f2bf(acc[t][j]);
    }
  }
}

__device__ __noinline__ void overflow_add(int r, int c, float v,
                                          const uint16_t* __restrict__ H16,
                                          float* __restrict__ out){
  const uint16_t* h = H16 + (size_t)c * OO;
  float* dst = out + (size_t)r * OO;
  for (int d = 0; d < OO; ++d) unsafeAtomicAdd(dst + d, v * bf2f(h[d]));
}

// ---- scatter: 1 edge/thread, 64B-padded counters (R5 A/B winner) ----
__global__ __launch_bounds__(256) void scatter_p_kernel(const int* __restrict__ rows,
                                                        const int* __restrict__ cols,
                                                        const float* __restrict__ vals,
                                                        const uint16_t* __restrict__ H16,
                                                        int* __restrict__ cnt,
                                                        int2* __restrict__ pay,
                                                        float* __restrict__ out, int E){
  int e = blockIdx.x * blockDim.x + threadIdx.x;
  if (e >= E) return;
  int r = rows[e], c = cols[e];
  float v = vals[e];
  int pos = atomicAdd(&cnt[(size_t)r * CSTR], 1);
  if (pos < CAP) pay[(size_t)r * CAP + pos] = make_int2(c, __float_as_int(v));
  else overflow_add(r, c, v, H16, out);
}

// ---- gather: one wave per row, k-unroll x8, zeroes counter for next pass, relu on last ----
template<bool LAST>
__global__ __launch_bounds__(256) void gatherz_kernel(int* __restrict__ cnt,
                                                      const int2* __restrict__ pay,
                                                      const uint16_t* __restrict__ H16,
                                                      float* __restrict__ out){
  const int lane = threadIdx.x & 63;
  const int row  = blockIdx.x * 4 + (threadIdx.x >> 6);
  if (row >= NN) return;
  int deg = cnt[(size_t)row * CSTR];
  if (lane == 0) cnt[(size_t)row * CSTR] = 0;
  if (deg > CAP) deg = CAP;

  float2 acc = *(const float2*)(out + (size_t)row * OO + lane * 2);
  int2 p = make_int2(0, 0);
  if (lane < deg) p = pay[(size_t)row * CAP + lane];
  const uint16_t* hb = H16 + lane * 2;

  int k = 0;
  for (; k + 8 <= deg; k += 8){
    int   c0 = __builtin_amdgcn_readlane(p.x, k);
    int   c1 = __builtin_amdgcn_readlane(p.x, k + 1);
    int   c2 = __builtin_amdgcn_readlane(p.x, k + 2);
    int   c3 = __builtin_amdgcn_readlane(p.x, k + 3);
    int   c4 = __builtin_amdgcn_readlane(p.x, k + 4);
    int   c5 = __builtin_amdgcn_readlane(p.x, k + 5);
    int   c6 = __builtin_amdgcn_readlane(p.x, k + 6);
    int   c7 = __builtin_amdgcn_readlane(p.x, k + 7);
    float v0 = __int_as_float(__builtin_amdgcn_readlane(p.y, k));
    float v1 = __int_as_float(__builtin_amdgcn_readlane(p.y, k + 1));
    float v2 = __int_as_float(__builtin_amdgcn_readlane(p.y, k + 2));
    float v3 = __int_as_float(__builtin_amdgcn_readlane(p.y, k + 3));
    float v4 = __int_as_float(__builtin_amdgcn_readlane(p.y, k + 4));
    float v5 = __int_as_float(__builtin_amdgcn_readlane(p.y, k + 5));
    float v6 = __int_as_float(__builtin_amdgcn_readlane(p.y, k + 6));
    float v7 = __int_as_float(__builtin_amdgcn_readlane(p.y, k + 7));
    uint32_t q0 = *(const uint32_t*)(hb + (size_t)c0 * OO);
    uint32_t q1 = *(const uint32_t*)(hb + (size_t)c1 * OO);
    uint32_t q2 = *(const uint32_t*)(hb + (size_t)c2 * OO);
    uint32_t q3 = *(const uint32_t*)(hb + (size_t)c3 * OO);
    uint32_t q4 = *(const uint32_t*)(hb + (size_t)c4 * OO);
    uint32_t q5 = *(const uint32_t*)(hb + (size_t)c5 * OO);
    uint32_t q6 = *(const uint32_t*)(hb + (size_t)c6 * OO);
    uint32_t q7 = *(const uint32_t*)(hb + (size_t)c7 * OO);
    acc.x += v0 * bf2f((uint16_t)(q0 & 0xFFFFu));  acc.y += v0 * bf2f((uint16_t)(q0 >> 16));
    acc.x += v1 * bf2f((uint16_t)(q1 & 0xFFFFu));  acc.y += v1 * bf2f((uint16_t)(q1 >> 16));
    acc.x += v2 * bf2f((uint16_t)(q2 & 0xFFFFu));  acc.y += v2 * bf2f((uint16_t)(q2 >> 16));
    acc.x += v3 * bf2f((uint16_t)(q3 & 0xFFFFu));  acc.y += v3 * bf2f((uint16_t)(q3 >> 16));
    acc.x += v4 * bf2f((uint16_t)(q4 & 0xFFFFu));  acc.y += v4 * bf2f((uint16_t)(q4 >> 16));
    acc.x += v5 * bf2f((uint16_t)(q5 & 0xFFFFu));  acc.y += v5 * bf2f((uint16_t)(q5 >> 16));
    acc.x += v6 * bf2f((uint16_t)(q6 & 0xFFFFu));  acc.y += v6 * bf2f((uint16_t)(q6 >> 16));
    acc.x += v7 * bf2f((uint16_t)(q7 & 0xFFFFu));  acc.y += v7 * bf2f((uint16_t)(q7 >> 16));
  }
  for (; k + 4 <= deg; k += 4){
    int   c0 = __builtin_amdgcn_readlane(p.x, k);
    int   c1 = __builtin_amdgcn_readlane(p.x, k + 1);
    int   c2 = __builtin_amdgcn_readlane(p.x, k + 2);
    int   c3 = __builtin_amdgcn_readlane(p.x, k + 3);
    float v0 = __int_as_float(__builtin_amdgcn_readlane(p.y, k));
    float v1 = __int_as_float(__builtin_amdgcn_readlane(p.y, k + 1));
    float v2 = __int_as_float(__builtin_amdgcn_readlane(p.y, k + 2));
    float v3 = __int_as_float(__builtin_amdgcn_readlane(p.y, k + 3));
    uint32_t q0 = *(const uint32_t*)(hb + (size_t)c0 * OO);
    uint32_t q1 = *(const uint32_t*)(hb + (size_t)c1 * OO);
    uint32_t q2 = *(const uint32_t*)(hb + (size_t)c2 * OO);
    uint32_t q3 = *(const uint32_t*)(hb + (size_t)c3 * OO);
    acc.x += v0 * bf2f((uint16_t)(q0 & 0xFFFFu));  acc.y += v0 * bf2f((uint16_t)(q0 >> 16));
    acc.x += v1 * bf2f((uint16_t)(q1 & 0xFFFFu));  acc.y += v1 * bf2f((uint16_t)(q1 >> 16));
    acc.x += v2 * bf2f((uint16_t)(q2 & 0xFFFFu));  acc.y += v2 * bf2f((uint16_t)(q2 >> 16));
    acc.x += v3 * bf2f((uint16_t)(q3 & 0xFFFFu));  acc.y += v3 * bf2f((uint16_t)(q3 >> 16));
  }
  for (; k < deg; ++k){
    int   cc = __builtin_amdgcn_readlane(p.x, k);
    float vv = __int_as_float(__builtin_amdgcn_readlane(p.y, k));
    uint32_t q = *(const uint32_t*)(hb + (size_t)cc * OO);
    acc.x += vv * bf2f((uint16_t)(q & 0xFFFFu));
    acc.y += vv * bf2f((uint16_t)(q >> 16));
  }
  if (LAST){ acc.x = fmaxf(acc.x, 0.f); acc.y = fmaxf(acc.y, 0.f); }
  *(float2*)(out + (size_t)row * OO + lane * 2) = acc;
}

// ---- fallback atomic spmm (R0-validated, only if ws too small) ----
__global__ __launch_bounds__(256) void spmm_kernel(const int* __restrict__ rows,
                                                   const int* __restrict__ cols,
                                                   const float* __restrict__ vals,
                                                   const uint16_t* __restrict__ H16,
                                                   float* __restrict__ out, int E){
  const int lane = threadIdx.x & 63;
  const int gwave = (int)((blockIdx.x * blockDim.x + threadIdx.x) >> 6);
  const int nw = (gridDim.x * blockDim.x) >> 6;
  for (int base = gwave * 64; base < E; base += nw * 64){
    int cnt = E - base; if (cnt > 64) cnt = 64;
    int r = 0, c = 0; float v = 0.f;
    if (lane < cnt){
      r = rows[base + lane]; c = cols[base + lane]; v = vals[base + lane];
    }
    for (int k = 0; k < cnt; ++k){
      int rr = __shfl(r, k);
      int cc = __shfl(c, k);
      float vv = __shfl(v, k);
      uint32_t pair = *(const uint32_t*)(H16 + (size_t)cc * OO + lane * 2);
      float* dst = out + (size_t)rr * OO + lane * 2;
      unsafeAtomicAdd(dst,     vv * bf2f((uint16_t)(pair & 0xFFFFu)));
      unsafeAtomicAdd(dst + 1, vv * bf2f((uint16_t)(pair >> 16)));
    }
  }
}

__global__ void relu_kernel(float* __restrict__ out, int n4){
  int i = blockIdx.x * blockDim.x + threadIdx.x;
  if (i < n4){
    float4 v = ((float4*)out)[i];
    v.x = fmaxf(v.x, 0.f); v.y = fmaxf(v.y, 0.f);
    v.z = fmaxf(v.z, 0.f); v.w = fmaxf(v.w, 0.f);
    ((float4*)out)[i] = v;
  }
}

extern "C" void kernel_launch(void* const* d_in, const int* in_sizes, int n_in,
                              void* d_out, int out_size, void* d_ws, size_t ws_size,
                              hipStream_t stream){
  const float* features = (const float*)d_in[0];
  const int*   rows     = (const int*)d_in[1];
  const int*   cols     = (const int*)d_in[2];
  const float* vals     = (const float*)d_in[3];
  const float* W        = (const float*)d_in[4];
  const float* Wc       = (const float*)d_in[5];
  float* out = (float*)d_out;
  const int E = in_sizes[1] / NS;

  char* ws = (char*)d_ws;
  uint16_t* X16 = (uint16_t*)ws;                        // 25,600,000
  uint16_t* Vt  = (uint16_t*)(ws + 25600000);           //    262,144
  uint16_t* H16 = (uint16_t*)(ws + 25862144);           // 25,600,000
  int*      cnt = (int*)     (ws + 51462144);           //  6,400,000 (100K x 64B)
  int2*     pay = (int2*)    (ws + 57862144);           // 25,600,000 (100K x 32 x 8B)
  const size_t NEEDED = 57862144 + (size_t)NN * CAP * 8;   // 83,462,144 <= known-good ws (>= 90,262,144)

  hipMemsetAsync(d_out, 0, (size_t)out_size * sizeof(float), stream);
  cast_bf16_kernel<<<(NN * DD / 4 + 255) / 256, 256, 0, stream>>>(features, X16, NN * DD / 4);
  vt_kernel<<<NS * OO, DD, 0, stream>>>(W, Wc, Vt);

  if (ws_size >= NEEDED){
    hipMemsetAsync(cnt, 0, (size_t)NN * CSTR * sizeof(int), stream);  // once; gather re-zeroes
    for (int s = 0; s < NS; ++s){
      gemm_kernel<<<(NN + 63) / 64, 256, 0, stream>>>(X16, Vt + (size_t)s * DD * OO, H16);
      scatter_p_kernel<<<(E + 255) / 256, 256, 0, stream>>>(
          rows + (size_t)s * E, cols + (size_t)s * E, vals + (size_t)s * E,
          H16, cnt, pay, out, E);
      if (s == NS - 1)
        gatherz_kernel<true><<<(NN + 3) / 4, 256, 0, stream>>>(cnt, pay, H16, out);
      else
        gatherz_kernel<false><<<(NN + 3) / 4, 256, 0, stream>>>(cnt, pay, H16, out);
    }
  } else {
    for (int s = 0; s < NS; ++s){
      gemm_kernel<<<(NN + 63) / 64, 256, 0, stream>>>(X16, Vt + (size_t)s * DD * OO, H16);
      spmm_kernel<<<4096, 256, 0, stream>>>(rows + (size_t)s * E, cols + (size_t)s * E,
                                            vals + (size_t)s * E, H16, out, E);
    }
    relu_kernel<<<(NN * OO / 4 + 255) / 256, 256, 0, stream>>>(out, NN * OO / 4);
  }
}